// Round 4
// baseline (522.790 us; speedup 1.0000x reference)
//
#include <hip/hip_runtime.h>

typedef unsigned short u16;
typedef unsigned int u32;

typedef __bf16 bf16x8 __attribute__((ext_vector_type(8)));
typedef float f32x4 __attribute__((ext_vector_type(4)));

// bf16 round-to-nearest-even from f32
__device__ __forceinline__ u16 f2bf(float f) {
    u32 u = __float_as_uint(f);
    return (u16)((u + 0x7fffu + ((u >> 16) & 1u)) >> 16);
}

// ---------------- Kernel A: prep (vmean + tnorm) ----------------
// grid.x = 8192 + 32, block 256 (4 waves).
// vmean blocks (bxx < 8192): one (b,t) per block. 16 lanes per n-row:
//   wave w, group g (lanes 16g..16g+15) handles n = 4w+g; lane l15 owns
//   d = {i*64 + l15*4 .. +4 | i=0..7} (8 independent float4 loads, each
//   instruction covers 4x 256B fully-coalesced segments).
//   ssq: per-lane partial + 4-step shfl within 16 lanes -> inv -> scale ->
//   cross-group butterfly (off 16,32) -> 8KB LDS combine across 4 waves ->
//   mean/16 -> bf16 -> vm[b][t][:].
// tnorm blocks (bxx >= 8192): 16 t_feat rows per block, one per (w,g).
__global__ __launch_bounds__(256, 4) void prep_kernel(
    const float* __restrict__ v,
    const float* __restrict__ tf,
    u16* __restrict__ vm,
    u16* __restrict__ tn,
    const int* __restrict__ splitp)
{
    const int tid  = threadIdx.x;
    const int w    = tid >> 6;
    const int lane = tid & 63;
    const int g    = lane >> 4;
    const int l15  = lane & 15;
    const int split = *splitp;
    const int bxx  = blockIdx.x;

    if (bxx >= 8192) {
        // ---- tnorm: row = (bxx-8192)*16 + 4w + g ----
        const int row = (bxx - 8192) * 16 + w * 4 + g;
        const float* rp = tf + (size_t)row * 512;
        float4 x[8];
#pragma unroll
        for (int i = 0; i < 8; i++)
            x[i] = *reinterpret_cast<const float4*>(rp + i * 64 + l15 * 4);
        float s = 0.f;
#pragma unroll
        for (int i = 0; i < 8; i++)
            s += x[i].x*x[i].x + x[i].y*x[i].y + x[i].z*x[i].z + x[i].w*x[i].w;
#pragma unroll
        for (int off = 1; off < 16; off <<= 1) s += __shfl_xor(s, off, 64);
        float inv = 1.0f;
        if (split == 1) inv = 1.0f / fmaxf(sqrtf(s), 1e-12f);
        u16* orow = tn + (size_t)row * 512;
#pragma unroll
        for (int i = 0; i < 8; i++) {
            uint2 pk;
            pk.x = (u32)f2bf(x[i].x*inv) | ((u32)f2bf(x[i].y*inv) << 16);
            pk.y = (u32)f2bf(x[i].z*inv) | ((u32)f2bf(x[i].w*inv) << 16);
            *reinterpret_cast<uint2*>(orow + i * 64 + l15 * 4) = pk;
        }
        return;
    }

    // ---- vmean: (b,t) = (bxx>>8, bxx&255), n = 4w+g ----
    const int b = bxx >> 8;
    const int t = bxx & 255;
    const int n = w * 4 + g;
    const float* rp = v + (((size_t)(b * 16 + n) * 256) + t) * 512;

    float4 x[8];
#pragma unroll
    for (int i = 0; i < 8; i++)
        x[i] = *reinterpret_cast<const float4*>(rp + i * 64 + l15 * 4);

    float s = 0.f;
#pragma unroll
    for (int i = 0; i < 8; i++)
        s += x[i].x*x[i].x + x[i].y*x[i].y + x[i].z*x[i].z + x[i].w*x[i].w;
#pragma unroll
    for (int off = 1; off < 16; off <<= 1) s += __shfl_xor(s, off, 64);
    float inv = 1.0f;
    if (split == 1) inv = 1.0f / fmaxf(sqrtf(s), 1e-12f);

#pragma unroll
    for (int i = 0; i < 8; i++) {
        x[i].x *= inv; x[i].y *= inv; x[i].z *= inv; x[i].w *= inv;
    }

    // cross-group butterfly: after this every lane holds the wave's 4-n sum
#pragma unroll
    for (int off = 16; off < 64; off <<= 1)
#pragma unroll
        for (int i = 0; i < 8; i++) {
            x[i].x += __shfl_xor(x[i].x, off, 64);
            x[i].y += __shfl_xor(x[i].y, off, 64);
            x[i].z += __shfl_xor(x[i].z, off, 64);
            x[i].w += __shfl_xor(x[i].w, off, 64);
        }

    // cross-wave combine via LDS: lane (g,l15) contributes chunks 2g, 2g+1
    __shared__ float lds[4][512];
#pragma unroll
    for (int j = 0; j < 2; j++) {
        const int i = 2 * g + j;
        *reinterpret_cast<float4*>(&lds[w][i * 64 + l15 * 4]) = x[i];
    }
    __syncthreads();

    float2 r; r.x = 0.f; r.y = 0.f;
#pragma unroll
    for (int w2 = 0; w2 < 4; w2++) {
        float2 p = *reinterpret_cast<const float2*>(&lds[w2][tid * 2]);
        r.x += p.x; r.y += p.y;
    }
    r.x *= 0.0625f; r.y *= 0.0625f;
    u32 packed = (u32)f2bf(r.x) | ((u32)f2bf(r.y) << 16);
    reinterpret_cast<u32*>(vm)[((size_t)(b * 256 + t) << 8) + tid] = packed;
}

// ---------------- Kernel B: direct-from-global MFMA GEMM ----------------
// out[b][c][t] = <tn[c,:], vm[b,t,:]> / tau.  Inputs (9 MB) are L2/L3-hot
// from kernel A -> no LDS staging, no barriers: each wave reads fragments
// straight from global and runs 16 k-steps of 4 MFMA.
// grid (8,4,32), block 256 = 4 waves (2x2), wave = 32c x 32t.
__global__ __launch_bounds__(256) void gemm_kernel(
    const u16* __restrict__ tn,
    const u16* __restrict__ vm,
    float* __restrict__ out)
{
    const int tid  = threadIdx.x;
    const int lane = tid & 63;
    const int wid  = tid >> 6;
    const int wm   = wid & 1;
    const int wn   = wid >> 1;
    const int quad = lane >> 4;
    const int l15  = lane & 15;

    const int c0 = blockIdx.x * 64 + wm * 32;
    const int t0 = blockIdx.y * 64 + wn * 32;
    const int b  = blockIdx.z;

    const u16* A0 = tn + (size_t)(c0 + l15) * 512 + quad * 8;
    const u16* B0 = vm + (size_t)b * 131072 + (size_t)(t0 + l15) * 512 + quad * 8;

    f32x4 acc[2][2] = {};
#pragma unroll 4
    for (int kk = 0; kk < 512; kk += 32) {
        bf16x8 af[2], bf[2];
#pragma unroll
        for (int i = 0; i < 2; i++)
            af[i] = *reinterpret_cast<const bf16x8*>(A0 + (size_t)i * 16 * 512 + kk);
#pragma unroll
        for (int j = 0; j < 2; j++)
            bf[j] = *reinterpret_cast<const bf16x8*>(B0 + (size_t)j * 16 * 512 + kk);
#pragma unroll
        for (int i = 0; i < 2; i++)
#pragma unroll
            for (int j = 0; j < 2; j++)
                acc[i][j] = __builtin_amdgcn_mfma_f32_16x16x32_bf16(
                    af[i], bf[j], acc[i][j], 0, 0, 0);
    }

    const float sc = 1.0f / 0.07f;
    float* ob = out + (size_t)b * 131072;  // 512*256
#pragma unroll
    for (int i = 0; i < 2; i++)
#pragma unroll
        for (int j = 0; j < 2; j++)
#pragma unroll
            for (int r = 0; r < 4; r++)
                ob[(c0 + i * 16 + quad * 4 + r) * 256 + (t0 + j * 16 + l15)]
                    = acc[i][j][r] * sc;
}

extern "C" void kernel_launch(void* const* d_in, const int* in_sizes, int n_in,
                              void* d_out, int out_size, void* d_ws, size_t ws_size,
                              hipStream_t stream) {
    const float* v_feat = (const float*)d_in[0];   // (32,16,256,512) f32
    const float* t_feat = (const float*)d_in[1];   // (512,512) f32
    const int*   splitp = (const int*)d_in[2];
    float* out = (float*)d_out;                    // (32,512,256) f32

    u16* tn = (u16*)d_ws;                 // 512*512 bf16    = 512 KB
    u16* vm = tn + 512 * 512;             // 32*256*512 bf16 = 8 MB

    prep_kernel<<<dim3(8192 + 32), dim3(256), 0, stream>>>(v_feat, t_feat, vm, tn, splitp);
    gemm_kernel<<<dim3(8, 4, 32), dim3(256), 0, stream>>>(tn, vm, out);
}

// Round 5
// 389.366 us; speedup vs baseline: 1.3427x; 1.3427x over previous
//
#include <hip/hip_runtime.h>

typedef unsigned short u16;
typedef unsigned int u32;

typedef __bf16 bf16x8 __attribute__((ext_vector_type(8)));
typedef float f32x4 __attribute__((ext_vector_type(4)));

// bf16 round-to-nearest-even from f32
__device__ __forceinline__ u16 f2bf(float f) {
    u32 u = __float_as_uint(f);
    return (u16)((u + 0x7fffu + ((u >> 16) & 1u)) >> 16);
}

// ---------------- Kernel A: prep (vmean + tnorm) ----------------
// grid.x = 8192 + 32, block 256 (4 waves).
// vmean blocks (bxx < 8192): one (b,t) per block. 16 lanes per n-row:
//   wave w, group g (lanes 16g..16g+15) handles n = 4w+g; lane l15 owns
//   d = {i*64 + l15*4 .. +4 | i=0..7} (8 independent float4 loads).
//   ssq: per-lane partial + 4-step shfl within 16 lanes -> inv -> scale ->
//   cross-group butterfly (off 16,32) -> 8KB LDS combine across 4 waves ->
//   mean/16 -> bf16 -> vm[b][t][:].
// NOTE: the LDS-combine write MUST be statically indexed (rule #20) — a
// runtime x[2*g+j] sends the whole x[8] array to scratch (measured r4:
// VGPR=32, WRITE_SIZE=342MB, 29% BW). Unrolled i + predicate keeps VGPRs.
// tnorm blocks (bxx >= 8192): 16 t_feat rows per block, one per (w,g).
__global__ __launch_bounds__(256, 4) void prep_kernel(
    const float* __restrict__ v,
    const float* __restrict__ tf,
    u16* __restrict__ vm,
    u16* __restrict__ tn,
    const int* __restrict__ splitp)
{
    const int tid  = threadIdx.x;
    const int w    = tid >> 6;
    const int lane = tid & 63;
    const int g    = lane >> 4;
    const int l15  = lane & 15;
    const int split = *splitp;
    const int bxx  = blockIdx.x;

    if (bxx >= 8192) {
        // ---- tnorm: row = (bxx-8192)*16 + 4w + g ----
        const int row = (bxx - 8192) * 16 + w * 4 + g;
        const float* rp = tf + (size_t)row * 512;
        float4 x[8];
#pragma unroll
        for (int i = 0; i < 8; i++)
            x[i] = *reinterpret_cast<const float4*>(rp + i * 64 + l15 * 4);
        float s = 0.f;
#pragma unroll
        for (int i = 0; i < 8; i++)
            s += x[i].x*x[i].x + x[i].y*x[i].y + x[i].z*x[i].z + x[i].w*x[i].w;
#pragma unroll
        for (int off = 1; off < 16; off <<= 1) s += __shfl_xor(s, off, 64);
        float inv = 1.0f;
        if (split == 1) inv = 1.0f / fmaxf(sqrtf(s), 1e-12f);
        u16* orow = tn + (size_t)row * 512;
#pragma unroll
        for (int i = 0; i < 8; i++) {
            uint2 pk;
            pk.x = (u32)f2bf(x[i].x*inv) | ((u32)f2bf(x[i].y*inv) << 16);
            pk.y = (u32)f2bf(x[i].z*inv) | ((u32)f2bf(x[i].w*inv) << 16);
            *reinterpret_cast<uint2*>(orow + i * 64 + l15 * 4) = pk;
        }
        return;
    }

    // ---- vmean: (b,t) = (bxx>>8, bxx&255), n = 4w+g ----
    const int b = bxx >> 8;
    const int t = bxx & 255;
    const int n = w * 4 + g;
    const float* rp = v + (((size_t)(b * 16 + n) * 256) + t) * 512;

    float4 x[8];
#pragma unroll
    for (int i = 0; i < 8; i++)
        x[i] = *reinterpret_cast<const float4*>(rp + i * 64 + l15 * 4);

    float s = 0.f;
#pragma unroll
    for (int i = 0; i < 8; i++)
        s += x[i].x*x[i].x + x[i].y*x[i].y + x[i].z*x[i].z + x[i].w*x[i].w;
#pragma unroll
    for (int off = 1; off < 16; off <<= 1) s += __shfl_xor(s, off, 64);
    float inv = 1.0f;
    if (split == 1) inv = 1.0f / fmaxf(sqrtf(s), 1e-12f);

#pragma unroll
    for (int i = 0; i < 8; i++) {
        x[i].x *= inv; x[i].y *= inv; x[i].z *= inv; x[i].w *= inv;
    }

    // cross-group butterfly: after this every lane holds the wave's 4-n sum
#pragma unroll
    for (int off = 16; off < 64; off <<= 1)
#pragma unroll
        for (int i = 0; i < 8; i++) {
            x[i].x += __shfl_xor(x[i].x, off, 64);
            x[i].y += __shfl_xor(x[i].y, off, 64);
            x[i].z += __shfl_xor(x[i].z, off, 64);
            x[i].w += __shfl_xor(x[i].w, off, 64);
        }

    // cross-wave combine via LDS. Statically indexed (i compile-time,
    // predicate on g) so x[] stays in VGPRs — see note above.
    __shared__ float lds[4][512];
#pragma unroll
    for (int i = 0; i < 8; i++) {
        if ((i >> 1) == g)
            *reinterpret_cast<float4*>(&lds[w][i * 64 + l15 * 4]) = x[i];
    }
    __syncthreads();

    float2 r; r.x = 0.f; r.y = 0.f;
#pragma unroll
    for (int w2 = 0; w2 < 4; w2++) {
        float2 p = *reinterpret_cast<const float2*>(&lds[w2][tid * 2]);
        r.x += p.x; r.y += p.y;
    }
    r.x *= 0.0625f; r.y *= 0.0625f;
    u32 packed = (u32)f2bf(r.x) | ((u32)f2bf(r.y) << 16);
    reinterpret_cast<u32*>(vm)[((size_t)(b * 256 + t) << 8) + tid] = packed;
}

// ---------------- Kernel B: direct-from-global MFMA GEMM ----------------
// out[b][c][t] = <tn[c,:], vm[b,t,:]> / tau.  Inputs (9 MB) are L2/L3-hot
// from kernel A -> no LDS staging, no barriers: each wave reads fragments
// straight from global and runs 16 k-steps of 4 MFMA.
// grid (8,4,32), block 256 = 4 waves (2x2), wave = 32c x 32t.
__global__ __launch_bounds__(256) void gemm_kernel(
    const u16* __restrict__ tn,
    const u16* __restrict__ vm,
    float* __restrict__ out)
{
    const int tid  = threadIdx.x;
    const int lane = tid & 63;
    const int wid  = tid >> 6;
    const int wm   = wid & 1;
    const int wn   = wid >> 1;
    const int quad = lane >> 4;
    const int l15  = lane & 15;

    const int c0 = blockIdx.x * 64 + wm * 32;
    const int t0 = blockIdx.y * 64 + wn * 32;
    const int b  = blockIdx.z;

    const u16* A0 = tn + (size_t)(c0 + l15) * 512 + quad * 8;
    const u16* B0 = vm + (size_t)b * 131072 + (size_t)(t0 + l15) * 512 + quad * 8;

    f32x4 acc[2][2] = {};
#pragma unroll 4
    for (int kk = 0; kk < 512; kk += 32) {
        bf16x8 af[2], bf[2];
#pragma unroll
        for (int i = 0; i < 2; i++)
            af[i] = *reinterpret_cast<const bf16x8*>(A0 + (size_t)i * 16 * 512 + kk);
#pragma unroll
        for (int j = 0; j < 2; j++)
            bf[j] = *reinterpret_cast<const bf16x8*>(B0 + (size_t)j * 16 * 512 + kk);
#pragma unroll
        for (int i = 0; i < 2; i++)
#pragma unroll
            for (int j = 0; j < 2; j++)
                acc[i][j] = __builtin_amdgcn_mfma_f32_16x16x32_bf16(
                    af[i], bf[j], acc[i][j], 0, 0, 0);
    }

    const float sc = 1.0f / 0.07f;
    float* ob = out + (size_t)b * 131072;  // 512*256
#pragma unroll
    for (int i = 0; i < 2; i++)
#pragma unroll
        for (int j = 0; j < 2; j++)
#pragma unroll
            for (int r = 0; r < 4; r++)
                ob[(c0 + i * 16 + quad * 4 + r) * 256 + (t0 + j * 16 + l15)]
                    = acc[i][j][r] * sc;
}

extern "C" void kernel_launch(void* const* d_in, const int* in_sizes, int n_in,
                              void* d_out, int out_size, void* d_ws, size_t ws_size,
                              hipStream_t stream) {
    const float* v_feat = (const float*)d_in[0];   // (32,16,256,512) f32
    const float* t_feat = (const float*)d_in[1];   // (512,512) f32
    const int*   splitp = (const int*)d_in[2];
    float* out = (float*)d_out;                    // (32,512,256) f32

    u16* tn = (u16*)d_ws;                 // 512*512 bf16    = 512 KB
    u16* vm = tn + 512 * 512;             // 32*256*512 bf16 = 8 MB

    prep_kernel<<<dim3(8192 + 32), dim3(256), 0, stream>>>(v_feat, t_feat, vm, tn, splitp);
    gemm_kernel<<<dim3(8, 4, 32), dim3(256), 0, stream>>>(tn, vm, out);
}

// Round 6
// 369.793 us; speedup vs baseline: 1.4137x; 1.0529x over previous
//
#include <hip/hip_runtime.h>

typedef unsigned short u16;
typedef unsigned int u32;

typedef __bf16 bf16x8 __attribute__((ext_vector_type(8)));
typedef float f32x4 __attribute__((ext_vector_type(4)));

// bf16 round-to-nearest-even from f32
__device__ __forceinline__ u16 f2bf(float f) {
    u32 u = __float_as_uint(f);
    return (u16)((u + 0x7fffu + ((u >> 16) & 1u)) >> 16);
}

// ---------------- Kernel A: prep (vmean + tnorm) ----------------
// grid.x = 8192 + 32, block 256 (4 waves).
// vmean blocks (bxx < 8192): one (b,t) per block. 16 lanes per n-row:
//   wave w, group g (lanes 16g..16g+15) handles n = 4w+g; lane l15 owns
//   d = {i*64 + l15*4 .. +4 | i=0..7} (8 independent float4 loads).
//   ssq: per-lane partial + 4-step shfl within 16 lanes -> inv -> scale ->
//   cross-group butterfly (off 16,32) -> 8KB LDS combine across 4 waves ->
//   mean/16 -> bf16 -> vm[b][t][:].
// NOTE: the LDS-combine write MUST be statically indexed (rule #20) — a
// runtime x[2*g+j] sends the whole x[8] array to scratch (measured r4:
// VGPR=32, WRITE_SIZE=342MB, 29% BW; fixed r5). Unrolled i + predicate.
// tnorm blocks (bxx >= 8192): 16 t_feat rows per block, one per (w,g).
__global__ __launch_bounds__(256, 4) void prep_kernel(
    const float* __restrict__ v,
    const float* __restrict__ tf,
    u16* __restrict__ vm,
    u16* __restrict__ tn,
    const int* __restrict__ splitp)
{
    const int tid  = threadIdx.x;
    const int w    = tid >> 6;
    const int lane = tid & 63;
    const int g    = lane >> 4;
    const int l15  = lane & 15;
    const int split = *splitp;
    const int bxx  = blockIdx.x;

    if (bxx >= 8192) {
        // ---- tnorm: row = (bxx-8192)*16 + 4w + g ----
        const int row = (bxx - 8192) * 16 + w * 4 + g;
        const float* rp = tf + (size_t)row * 512;
        float4 x[8];
#pragma unroll
        for (int i = 0; i < 8; i++)
            x[i] = *reinterpret_cast<const float4*>(rp + i * 64 + l15 * 4);
        float s = 0.f;
#pragma unroll
        for (int i = 0; i < 8; i++)
            s += x[i].x*x[i].x + x[i].y*x[i].y + x[i].z*x[i].z + x[i].w*x[i].w;
#pragma unroll
        for (int off = 1; off < 16; off <<= 1) s += __shfl_xor(s, off, 64);
        float inv = 1.0f;
        if (split == 1) inv = 1.0f / fmaxf(sqrtf(s), 1e-12f);
        u16* orow = tn + (size_t)row * 512;
#pragma unroll
        for (int i = 0; i < 8; i++) {
            uint2 pk;
            pk.x = (u32)f2bf(x[i].x*inv) | ((u32)f2bf(x[i].y*inv) << 16);
            pk.y = (u32)f2bf(x[i].z*inv) | ((u32)f2bf(x[i].w*inv) << 16);
            *reinterpret_cast<uint2*>(orow + i * 64 + l15 * 4) = pk;
        }
        return;
    }

    // ---- vmean: (b,t) = (bxx>>8, bxx&255), n = 4w+g ----
    const int b = bxx >> 8;
    const int t = bxx & 255;
    const int n = w * 4 + g;
    const float* rp = v + (((size_t)(b * 16 + n) * 256) + t) * 512;

    float4 x[8];
#pragma unroll
    for (int i = 0; i < 8; i++)
        x[i] = *reinterpret_cast<const float4*>(rp + i * 64 + l15 * 4);

    float s = 0.f;
#pragma unroll
    for (int i = 0; i < 8; i++)
        s += x[i].x*x[i].x + x[i].y*x[i].y + x[i].z*x[i].z + x[i].w*x[i].w;
#pragma unroll
    for (int off = 1; off < 16; off <<= 1) s += __shfl_xor(s, off, 64);
    float inv = 1.0f;
    if (split == 1) inv = 1.0f / fmaxf(sqrtf(s), 1e-12f);

#pragma unroll
    for (int i = 0; i < 8; i++) {
        x[i].x *= inv; x[i].y *= inv; x[i].z *= inv; x[i].w *= inv;
    }

    // cross-group butterfly: after this every lane holds the wave's 4-n sum
#pragma unroll
    for (int off = 16; off < 64; off <<= 1)
#pragma unroll
        for (int i = 0; i < 8; i++) {
            x[i].x += __shfl_xor(x[i].x, off, 64);
            x[i].y += __shfl_xor(x[i].y, off, 64);
            x[i].z += __shfl_xor(x[i].z, off, 64);
            x[i].w += __shfl_xor(x[i].w, off, 64);
        }

    // cross-wave combine via LDS. Statically indexed (i compile-time,
    // predicate on g) so x[] stays in VGPRs — see note above.
    __shared__ float lds[4][512];
#pragma unroll
    for (int i = 0; i < 8; i++) {
        if ((i >> 1) == g)
            *reinterpret_cast<float4*>(&lds[w][i * 64 + l15 * 4]) = x[i];
    }
    __syncthreads();

    float2 r; r.x = 0.f; r.y = 0.f;
#pragma unroll
    for (int w2 = 0; w2 < 4; w2++) {
        float2 p = *reinterpret_cast<const float2*>(&lds[w2][tid * 2]);
        r.x += p.x; r.y += p.y;
    }
    r.x *= 0.0625f; r.y *= 0.0625f;
    u32 packed = (u32)f2bf(r.x) | ((u32)f2bf(r.y) << 16);
    reinterpret_cast<u32*>(vm)[((size_t)(b * 256 + t) << 8) + tid] = packed;
}

// ---- Kernel B: out[b][c][t] = <tn[c,:], vm[b,t,:]> / tau.
// Reverted to the round-0 harness-verified LDS-staged structure: direct
// global fragment reads (r5) duplicated panel traffic in 64B granules
// (~512MB L2/L3) and was latency-bound; LDS staging reads each panel
// element once per block with 128B-coalesced loads.
// grid: (cTiles=4, tTiles=4, b=32) = 512 blocks, block 256 = 4 waves.
// wave (wm=w&1, wn=w>>1) computes 64c x 32t via 4x2 frags of 16x16x32.
__global__ __launch_bounds__(256) void gemm_kernel(const u16* __restrict__ tn,
                                                   const u16* __restrict__ vm,
                                                   float* __restrict__ out) {
    const int bx   = blockIdx.x;   // c tile (128 wide)
    const int by   = blockIdx.y;   // t tile (64 wide)
    const int b    = blockIdx.z;
    const int tid  = threadIdx.x;
    const int lane = tid & 63;
    const int wid  = tid >> 6;
    const int wm   = wid & 1;      // c dir (64 each)
    const int wn   = wid >> 1;     // t dir (32 each)
    const int quad = lane >> 4;
    const int l15  = lane & 15;

    // +8 bf16 pad per row -> 144B stride: <=2-way LDS conflicts (free)
    __shared__ u16 At[128 * 72];
    __shared__ u16 Bt[64 * 72];

    const int c0 = bx * 128, t0 = by * 64;
    f32x4 acc[4][2] = {};

    const int lrow = tid >> 3;        // 0..31 (staging row base)
    const int lcol = (tid & 7) * 8;   // staging col in elements

    const uint4* gA = reinterpret_cast<const uint4*>(tn);
    const uint4* gB = reinterpret_cast<const uint4*>(vm) + (size_t)b * 256 * 64;

    for (int k0 = 0; k0 < 512; k0 += 64) {
#pragma unroll
        for (int it = 0; it < 4; it++) {
            int row = lrow + it * 32;
            uint4 av = gA[(c0 + row) * 64 + (k0 >> 3) + (tid & 7)];
            *reinterpret_cast<uint4*>(&At[row * 72 + lcol]) = av;
        }
#pragma unroll
        for (int it = 0; it < 2; it++) {
            int row = lrow + it * 32;
            uint4 bv = gB[(t0 + row) * 64 + (k0 >> 3) + (tid & 7)];
            *reinterpret_cast<uint4*>(&Bt[row * 72 + lcol]) = bv;
        }
        __syncthreads();
#pragma unroll
        for (int kk = 0; kk < 64; kk += 32) {
            bf16x8 af[4], bfr[2];
#pragma unroll
            for (int i = 0; i < 4; i++)
                af[i] = *reinterpret_cast<const bf16x8*>(
                    &At[(wm * 64 + i * 16 + l15) * 72 + kk + quad * 8]);
#pragma unroll
            for (int j = 0; j < 2; j++)
                bfr[j] = *reinterpret_cast<const bf16x8*>(
                    &Bt[(wn * 32 + j * 16 + l15) * 72 + kk + quad * 8]);
#pragma unroll
            for (int i = 0; i < 4; i++)
#pragma unroll
                for (int j = 0; j < 2; j++)
                    acc[i][j] = __builtin_amdgcn_mfma_f32_16x16x32_bf16(
                        af[i], bfr[j], acc[i][j], 0, 0, 0);
        }
        __syncthreads();
    }

    const float s = 1.0f / 0.07f;
    float* ob = out + (size_t)b * 131072;  // 512*256
#pragma unroll
    for (int i = 0; i < 4; i++)
#pragma unroll
        for (int j = 0; j < 2; j++)
#pragma unroll
            for (int r = 0; r < 4; r++) {
                int c = c0 + wm * 64 + i * 16 + quad * 4 + r;
                int t = t0 + wn * 32 + j * 16 + l15;
                ob[c * 256 + t] = acc[i][j][r] * s;
            }
}

extern "C" void kernel_launch(void* const* d_in, const int* in_sizes, int n_in,
                              void* d_out, int out_size, void* d_ws, size_t ws_size,
                              hipStream_t stream) {
    const float* v_feat = (const float*)d_in[0];   // (32,16,256,512) f32
    const float* t_feat = (const float*)d_in[1];   // (512,512) f32
    const int*   splitp = (const int*)d_in[2];
    float* out = (float*)d_out;                    // (32,512,256) f32

    u16* tn = (u16*)d_ws;                 // 512*512 bf16    = 512 KB
    u16* vm = tn + 512 * 512;             // 32*256*512 bf16 = 8 MB

    prep_kernel<<<dim3(8192 + 32), dim3(256), 0, stream>>>(v_feat, t_feat, vm, tn, splitp);
    gemm_kernel<<<dim3(4, 4, 32), dim3(256), 0, stream>>>(tn, vm, out);
}